// Round 3
// baseline (286.792 us; speedup 1.0000x reference)
//
#include <hip/hip_runtime.h>

// SpatioConvLayer: B=16, C_IN=C_OUT=64, T=12, N=1024, KS=3
#define NB   16
#define NC   64
#define NT   12
#define NN   1024
#define NKS  3

typedef float  f32x4  __attribute__((ext_vector_type(4)));
typedef short  s16x8  __attribute__((ext_vector_type(8)));
typedef unsigned short u16x4 __attribute__((ext_vector_type(4)));

__device__ __forceinline__ unsigned short f2bf(float f) {
    union { float f; unsigned u; } v; v.f = f;
    unsigned r = v.u + 0x7FFFu + ((v.u >> 16) & 1u);   // RNE
    return (unsigned short)(r >> 16);
}

// Workspace layout (31,481,856 B total):
//   xbf  @ 0         : bf16 x, same [b,c,t,n] order          (25,165,824 B)
//   kb   @ 25165824  : bf16 kernel, [mt=16][nb=32][j=192][nn=32] (6,291,456 B)
//   thbf @ 31457280  : bf16 theta^T, [o=64][ck=192]          (24,576 B)
#define XBF_OFF  0
#define KB_OFF   25165824
#define TH_OFF   31457280

// ---------------- prep: convert + transpose once ----------------
__global__ __launch_bounds__(256)
void spatio_prep(const float* __restrict__ x, const float* __restrict__ kern,
                 const float* __restrict__ theta,
                 unsigned short* __restrict__ xbf, unsigned short* __restrict__ kb,
                 unsigned short* __restrict__ thbf)
{
    const int id = blockIdx.x * 256 + threadIdx.x;    // grid covers 3,145,728 ids

    // x -> bf16 (coalesced float4 -> u16x4)
    {
        float4 v = ((const float4*)x)[id];
        u16x4 w;
        w.x = f2bf(v.x); w.y = f2bf(v.y); w.z = f2bf(v.z); w.w = f2bf(v.w);
        ((u16x4*)xbf)[id] = w;
    }
    // kernel -> bf16, transposed panels Kb[mt][nb][j][nn]
    if (id < 786432) {                                 // 1024 * 768 float4s
        float4 v = ((const float4*)kern)[id];
        int n    = id / 768;                           // row (n)
        int q    = id - n * 768;
        int gcol = q * 4;                              // 4-aligned => same mt,k for all 4
        int k    = gcol >> 10;
        int mres = gcol & 1023;
        int mt   = mres >> 6;
        int mm   = mres & 63;
        int j    = k * 64 + mm;
        int nb   = n >> 5, nn = n & 31;
        size_t base = (((size_t)(mt * 32 + nb) * 192 + j) * 32 + nn);
        kb[base]      = f2bf(v.x);
        kb[base + 32] = f2bf(v.y);
        kb[base + 64] = f2bf(v.z);
        kb[base + 96] = f2bf(v.w);
    }
    // theta -> thbf[o][k*64+c]  (stage-2 A-operand order)
    if (id < 12288) {
        int row = id >> 6, o = id & 63;                // row = c*3 + k
        int c = row / 3, k = row - 3 * c;
        thbf[o * 192 + k * 64 + c] = f2bf(theta[id]);
    }
}

// ---------------- main: barrier-free MFMA GEMM + fused stage 2 ----------------
__global__ __launch_bounds__(256, 3)
void spatio_main(const unsigned short* __restrict__ xbf,
                 const unsigned short* __restrict__ kb,
                 const unsigned short* __restrict__ thbf,
                 const float* __restrict__ x, const float* __restrict__ bias,
                 float* __restrict__ out)
{
    // row stride 200 u16 = 400 B (multiple of 16 -> b128-aligned), cols 0..191 used
    __shared__ __attribute__((aligned(128))) unsigned short xmT[64][200]; // 25,600 B

    const int tid  = threadIdx.x;
    const int g    = blockIdx.x;          // bt-pair 0..95
    const int mt   = blockIdx.y;          // m-tile 0..15
    const int m_base = mt * 64;
    const int lane = tid & 63;
    const int wid  = tid >> 6;
    const int wm   = wid & 1;             // bt half
    const int wn   = wid >> 1;            // 96-col half
    const int quad = lane >> 4;
    const int l16  = lane & 15;

    // per-lane fragment pointers (all contiguous 16B loads)
    const int bt = 2 * g + wm;
    const int bb = bt / NT, tt = bt % NT;
    const unsigned short* ap[4];
#pragma unroll
    for (int i = 0; i < 4; ++i) {
        int c = 16 * i + l16;
        ap[i] = xbf + ((size_t)((bb * NC + c) * NT + tt)) * NN + quad * 8;
    }
    const unsigned short* bp[6];
#pragma unroll
    for (int jj = 0; jj < 6; ++jj) {
        int J = 96 * wn + 16 * jj + l16;
        bp[jj] = kb + ((size_t)(mt * 32) * 192 + J) * 32 + quad * 8;
    }

    f32x4 acc[4][6];
#pragma unroll
    for (int i = 0; i < 4; ++i)
#pragma unroll
        for (int j = 0; j < 6; ++j) acc[i][j] = (f32x4){0.f, 0.f, 0.f, 0.f};

    // ===== stage 1: xm = x @ K  — no LDS, no barriers =====
    for (int it = 0; it < 32; ++it) {
        s16x8 af[4], bf[6];
#pragma unroll
        for (int i = 0; i < 4; ++i) { af[i] = *(const s16x8*)ap[i]; ap[i] += 32; }
#pragma unroll
        for (int j = 0; j < 6; ++j) { bf[j] = *(const s16x8*)bp[j]; bp[j] += 6144; }
#pragma unroll
        for (int i = 0; i < 4; ++i)
#pragma unroll
            for (int j = 0; j < 6; ++j)
                acc[i][j] = __builtin_amdgcn_mfma_f32_16x16x32_bf16(af[i], bf[j], acc[i][j], 0, 0, 0);
    }

    // ===== stage 2: gc = th^T @ xm, one bt per pass =====
    for (int pass = 0; pass < 2; ++pass) {
        __syncthreads();               // previous pass reads done / LDS free
        if (wm == pass) {
#pragma unroll
            for (int i = 0; i < 4; ++i)
#pragma unroll
                for (int j = 0; j < 6; ++j) {
                    int J  = 96 * wn + 16 * j + l16;
                    int kk = J >> 6, mm = J & 63;
                    int ck0 = kk * 64 + 16 * i + 4 * quad;
                    u16x4 w;
                    w.x = f2bf(acc[i][j].x); w.y = f2bf(acc[i][j].y);
                    w.z = f2bf(acc[i][j].z); w.w = f2bf(acc[i][j].w);
                    *(u16x4*)&xmT[mm][ck0] = w;
                }
        }
        __syncthreads();

        f32x4 acc2[4];
#pragma unroll
        for (int j = 0; j < 4; ++j) acc2[j] = (f32x4){0.f, 0.f, 0.f, 0.f};
#pragma unroll
        for (int ks = 0; ks < 6; ++ks) {       // K = 192
            s16x8 a2 = *(const s16x8*)(thbf + (size_t)(16 * wid + l16) * 192 + ks * 32 + quad * 8);
#pragma unroll
            for (int j = 0; j < 4; ++j) {
                s16x8 b2 = *(const s16x8*)&xmT[16 * j + l16][ks * 32 + quad * 8];
                acc2[j] = __builtin_amdgcn_mfma_f32_16x16x32_bf16(a2, b2, acc2[j], 0, 0, 0);
            }
        }

        // epilogue: out = relu(gc + bias + x)
        const int bt2 = 2 * g + pass;
        const int b2 = bt2 / NT, t2 = bt2 % NT;
#pragma unroll
        for (int j = 0; j < 4; ++j) {
            int mm = 16 * j + l16;
#pragma unroll
            for (int r = 0; r < 4; ++r) {
                int o = 16 * wid + 4 * quad + r;
                size_t idx = (((size_t)(b2 * NC + o) * NT + t2) * NN) + m_base + mm;
                float v = acc2[j][r] + bias[o] + x[idx];
                out[idx] = fmaxf(v, 0.f);
            }
        }
    }
}

extern "C" void kernel_launch(void* const* d_in, const int* in_sizes, int n_in,
                              void* d_out, int out_size, void* d_ws, size_t ws_size,
                              hipStream_t stream) {
    const float* x     = (const float*)d_in[0];
    const float* kern  = (const float*)d_in[1];
    const float* theta = (const float*)d_in[2];
    const float* bias  = (const float*)d_in[3];
    float* out = (float*)d_out;
    (void)in_sizes; (void)n_in; (void)out_size; (void)ws_size;

    unsigned short* xbf  = (unsigned short*)((char*)d_ws + XBF_OFF);
    unsigned short* kbp  = (unsigned short*)((char*)d_ws + KB_OFF);
    unsigned short* thbf = (unsigned short*)((char*)d_ws + TH_OFF);

    hipLaunchKernelGGL(spatio_prep, dim3(12288), dim3(256), 0, stream,
                       x, kern, theta, xbf, kbp, thbf);
    hipLaunchKernelGGL(spatio_main, dim3(96, 16), dim3(256), 0, stream,
                       xbf, kbp, thbf, x, bias, out);
}

// Round 4
// 228.060 us; speedup vs baseline: 1.2575x; 1.2575x over previous
//
#include <hip/hip_runtime.h>

// SpatioConvLayer: B=16, C_IN=C_OUT=64, T=12, N=1024, KS=3
#define NB   16
#define NC   64
#define NT   12
#define NN   1024
#define NKS  3

typedef float  f32x4  __attribute__((ext_vector_type(4)));
typedef short  s16x8  __attribute__((ext_vector_type(8)));
typedef unsigned short u16x4 __attribute__((ext_vector_type(4)));
typedef unsigned short u16x8 __attribute__((ext_vector_type(8)));

__device__ __forceinline__ unsigned short f2bf(float f) {
    union { float f; unsigned u; } v; v.f = f;
    unsigned r = v.u + 0x7FFFu + ((v.u >> 16) & 1u);   // RNE
    return (unsigned short)(r >> 16);
}

// async 16-B global -> LDS (lane-linear dest: wave-uniform base + lane*16)
__device__ __forceinline__ void cp16(const void* g, void* l) {
    __builtin_amdgcn_global_load_lds(
        (const __attribute__((address_space(1))) unsigned int*)g,
        (__attribute__((address_space(3))) unsigned int*)l, 16, 0, 0);
}

// Workspace layout:
//   apan @ 0        : bf16 A-panels [g4=48][nb=32][slot=1024] x 16B   (25,165,824 B)
//                     slot = row*4 + p ; row = bl*64+c (bl=bt-4*g4) ; p = d ^ (row&3),
//                     d = n-chunk (8 elems) within the 32-n tile  (XOR bank swizzle)
//   kb   @ 25165824 : bf16 B-panels [mt=16][nb=32][slot=768] x 16B   (6,291,456 B)
//                     slot = j*4 + p ; j = k*64+mm ; p = d ^ (j&3)
//   thbf @ 31457280 : bf16 theta^T [o=64][ck=192]                    (24,576 B)
#define APAN_OFF 0
#define KB_OFF   25165824
#define TH_OFF   31457280

// ---------------- prep: convert + transpose + swizzle once ----------------
__global__ __launch_bounds__(256)
void spatio_prep(const float* __restrict__ x, const float* __restrict__ kern,
                 const float* __restrict__ theta,
                 unsigned short* __restrict__ apan, unsigned short* __restrict__ kb,
                 unsigned short* __restrict__ thbf)
{
    const int blk = blockIdx.x;
    const int tid = threadIdx.x;

    if (blk < 6144) {
        // ---- A panels: 1,572,864 threads, one 16-B slot each ----
        int id   = blk * 256 + tid;
        int slot = id & 1023;
        int g4nb = id >> 10;
        int nb   = g4nb & 31, g4 = g4nb >> 5;
        int row  = slot >> 2, p = slot & 3;
        int d    = p ^ (row & 3);
        int bl   = row >> 6, c = row & 63;
        int bt   = 4 * g4 + bl;
        int b    = bt / NT, t = bt - NT * b;
        const float* src = x + ((size_t)((b * NC + c) * NT + t)) * NN + nb * 32 + d * 8;
        float4 a0 = ((const float4*)src)[0];
        float4 a1 = ((const float4*)src)[1];
        u16x8 w;
        w[0] = f2bf(a0.x); w[1] = f2bf(a0.y); w[2] = f2bf(a0.z); w[3] = f2bf(a0.w);
        w[4] = f2bf(a1.x); w[5] = f2bf(a1.y); w[6] = f2bf(a1.z); w[7] = f2bf(a1.w);
        ((u16x8*)apan)[id] = w;
    } else if (blk < 6528) {
        // ---- B panels: 98,304 threads, one 64-B row (4 swizzled chunks) each ----
        int id   = (blk - 6144) * 256 + tid;
        int j    = id % 192;
        int rest = id / 192;
        int nb   = rest & 31, mt = rest >> 5;
        int k    = j >> 6, mm = j & 63;
        int col  = (k << 10) + (mt << 6) + mm;
        size_t base = ((size_t)(mt * 32 + nb) * 768) + j * 4;
#pragma unroll
        for (int d = 0; d < 4; ++d) {
            u16x8 w;
#pragma unroll
            for (int i = 0; i < 8; ++i) {
                int n = nb * 32 + d * 8 + i;
                w[i] = f2bf(kern[(size_t)n * (NKS * NN) + col]);
            }
            ((u16x8*)kb)[base + (d ^ (j & 3))] = w;
        }
    } else {
        // ---- theta^T: thbf[o][k*64+c] ----
        int id = (blk - 6528) * 256 + tid;
        if (id < 12288) {
            int row = id >> 6, o = id & 63;   // row = c*3 + k
            int c = row / 3, k = row - 3 * c;
            thbf[o * 192 + k * 64 + c] = f2bf(theta[id]);
        }
    }
}

// ---------------- main: 256x192 tile, global_load_lds staging, fused stage 2 ----------------
__global__ __launch_bounds__(256, 2)
void spatio_main(const unsigned short* __restrict__ apan,
                 const unsigned short* __restrict__ kb,
                 const unsigned short* __restrict__ thbf,
                 const float* __restrict__ x, const float* __restrict__ bias,
                 float* __restrict__ out)
{
    // LDS union: stage1 As[256][32] @0 (16 KB) + Bs[192][32] @16384 (12 KB)
    //            stage2 xm0[64][200] @0 (25.6 KB) + xm1[64][200] @25600 (25.6 KB)
    __shared__ __attribute__((aligned(128))) char smem[51200];
    unsigned short (*As)[32]  = (unsigned short (*)[32])smem;
    unsigned short (*Bs)[32]  = (unsigned short (*)[32])(smem + 16384);
    unsigned short (*xm0)[200] = (unsigned short (*)[200])smem;
    unsigned short (*xm1)[200] = (unsigned short (*)[200])(smem + 25600);

    const int tid  = threadIdx.x;
    const int g4   = blockIdx.x;          // 4-bt group 0..47
    const int mt   = blockIdx.y;          // m-tile 0..15
    const int m_base = mt * 64;
    const int lane = tid & 63;
    const int wid  = tid >> 6;            // 0..3
    const int wr   = wid & 1;             // row half (128 rows = 2 bt)
    const int wn   = wid >> 1;            // col half (96 j)
    const int quad = lane >> 4;
    const int l16  = lane & 15;
    const int pofs = (quad ^ (l16 & 3)) * 8;   // swizzled 16-B chunk, in u16 units

    const char* apan_c = (const char*)apan + ((size_t)g4 << 19);   // g4*32*1024*16
    const char* kb_c   = (const char*)kb + ((size_t)mt * 32 * 768 * 16);

    f32x4 acc[8][6];
#pragma unroll
    for (int i = 0; i < 8; ++i)
#pragma unroll
        for (int j = 0; j < 6; ++j) acc[i][j] = (f32x4){0.f, 0.f, 0.f, 0.f};

    // ===== stage 1: xm = x @ K ; K-loop over n (32 iters of 32) =====
    for (int it = 0; it < 32; ++it) {
        __syncthreads();                   // previous iter's frag reads done
        {
            const char* asrc = apan_c + ((size_t)it << 14);        // it*16384
            const char* bsrc = kb_c + ((size_t)it * 12288);
#pragma unroll
            for (int i = 0; i < 4; ++i)
                cp16(asrc + (i * 256 + tid) * 16, smem + (i * 256 + tid) * 16);
#pragma unroll
            for (int i = 0; i < 3; ++i)
                cp16(bsrc + (i * 256 + tid) * 16, smem + 16384 + (i * 256 + tid) * 16);
        }
        __syncthreads();                   // vmcnt(0) drained by compiler before barrier

        s16x8 af[8], bf[6];
#pragma unroll
        for (int rb = 0; rb < 8; ++rb)
            af[rb] = *(const s16x8*)&As[128 * wr + 16 * rb + l16][pofs];
#pragma unroll
        for (int jb = 0; jb < 6; ++jb)
            bf[jb] = *(const s16x8*)&Bs[96 * wn + 16 * jb + l16][pofs];
#pragma unroll
        for (int rb = 0; rb < 8; ++rb)
#pragma unroll
            for (int jb = 0; jb < 6; ++jb)
                acc[rb][jb] = __builtin_amdgcn_mfma_f32_16x16x32_bf16(af[rb], bf[jb], acc[rb][jb], 0, 0, 0);
    }

    // ===== stage 2: gc = th^T @ xm ; 2 passes x 2 bt =====
    for (int pass = 0; pass < 2; ++pass) {
        __syncthreads();               // stage-1 reads / previous pass reads done
        if (wr == pass) {
            // write acc -> xm{0,1}[mm][k*64+c] (B-operand layout for stage 2)
#pragma unroll
            for (int rb = 0; rb < 8; ++rb) {
                unsigned short (*dst)[200] = (rb < 4) ? xm0 : xm1;
                int ck0 = 16 * (rb & 3) + 4 * quad;
#pragma unroll
                for (int jb = 0; jb < 6; ++jb) {
                    int J  = 96 * wn + 16 * jb + l16;
                    int kk = J >> 6, mm = J & 63;
                    u16x4 w;
                    w.x = f2bf(acc[rb][jb].x); w.y = f2bf(acc[rb][jb].y);
                    w.z = f2bf(acc[rb][jb].z); w.w = f2bf(acc[rb][jb].w);
                    *(u16x4*)&dst[mm][kk * 64 + ck0] = w;
                }
            }
        }
        __syncthreads();

        const int sel = wid & 1;       // which bt of the pass
        const int oh  = wid >> 1;      // o half (32 rows)
        unsigned short (*srcT)[200] = sel ? xm1 : xm0;

        f32x4 acc2[2][4];
#pragma unroll
        for (int ob = 0; ob < 2; ++ob)
#pragma unroll
            for (int j = 0; j < 4; ++j) acc2[ob][j] = (f32x4){0.f, 0.f, 0.f, 0.f};

#pragma unroll
        for (int ks = 0; ks < 6; ++ks) {       // K = 192
            s16x8 a2[2];
#pragma unroll
            for (int ob = 0; ob < 2; ++ob)
                a2[ob] = *(const s16x8*)(thbf + (size_t)(32 * oh + 16 * ob + l16) * 192 + ks * 32 + quad * 8);
#pragma unroll
            for (int jb = 0; jb < 4; ++jb) {
                s16x8 b2 = *(const s16x8*)&srcT[16 * jb + l16][ks * 32 + quad * 8];
#pragma unroll
                for (int ob = 0; ob < 2; ++ob)
                    acc2[ob][jb] = __builtin_amdgcn_mfma_f32_16x16x32_bf16(a2[ob], b2, acc2[ob][jb], 0, 0, 0);
            }
        }

        // epilogue: out = relu(gc + bias + x)
        const int bt = 4 * g4 + 2 * pass + sel;
        const int b2 = bt / NT, t2 = bt - NT * b2;
#pragma unroll
        for (int ob = 0; ob < 2; ++ob)
#pragma unroll
            for (int jb = 0; jb < 4; ++jb) {
                int mm = 16 * jb + l16;
#pragma unroll
                for (int r = 0; r < 4; ++r) {
                    int o = 32 * oh + 16 * ob + 4 * quad + r;
                    size_t idx = (((size_t)(b2 * NC + o) * NT + t2) * NN) + m_base + mm;
                    float v = acc2[ob][jb][r] + bias[o] + x[idx];
                    out[idx] = fmaxf(v, 0.f);
                }
            }
    }
}

extern "C" void kernel_launch(void* const* d_in, const int* in_sizes, int n_in,
                              void* d_out, int out_size, void* d_ws, size_t ws_size,
                              hipStream_t stream) {
    const float* x     = (const float*)d_in[0];
    const float* kern  = (const float*)d_in[1];
    const float* theta = (const float*)d_in[2];
    const float* bias  = (const float*)d_in[3];
    float* out = (float*)d_out;
    (void)in_sizes; (void)n_in; (void)out_size; (void)ws_size;

    unsigned short* apan = (unsigned short*)((char*)d_ws + APAN_OFF);
    unsigned short* kbp  = (unsigned short*)((char*)d_ws + KB_OFF);
    unsigned short* thbf = (unsigned short*)((char*)d_ws + TH_OFF);

    hipLaunchKernelGGL(spatio_prep, dim3(6576), dim3(256), 0, stream,
                       x, kern, theta, apan, kbp, thbf);
    hipLaunchKernelGGL(spatio_main, dim3(48, 16), dim3(256), 0, stream,
                       apan, kbp, thbf, x, bias, out);
}

// Round 5
// 188.579 us; speedup vs baseline: 1.5208x; 1.2094x over previous
//
#include <hip/hip_runtime.h>

// SpatioConvLayer: B=16, C_IN=C_OUT=64, T=12, N=1024, KS=3
#define NB   16
#define NC   64
#define NT   12
#define NN   1024
#define NKS  3

typedef float  f32x4  __attribute__((ext_vector_type(4)));
typedef short  s16x8  __attribute__((ext_vector_type(8)));
typedef unsigned short u16x4 __attribute__((ext_vector_type(4)));
typedef unsigned short u16x8 __attribute__((ext_vector_type(8)));
typedef unsigned short ush;

__device__ __forceinline__ ush f2bf(float f) {
    union { float f; unsigned u; } v; v.f = f;
    unsigned r = v.u + 0x7FFFu + ((v.u >> 16) & 1u);   // RNE
    return (ush)(r >> 16);
}
__device__ __forceinline__ float bf2f(ush h) {
    union { unsigned u; float f; } v; v.u = ((unsigned)h) << 16;
    return v.f;
}

// async 16-B global -> LDS (dest must be wave-uniform base + lane*16)
__device__ __forceinline__ void cp16(const void* g, void* l) {
    __builtin_amdgcn_global_load_lds(
        (const __attribute__((address_space(1))) unsigned int*)g,
        (__attribute__((address_space(3))) unsigned int*)l, 16, 0, 0);
}

// Workspace layout:
//   apan @ 0        : bf16 A-panels [g2=96][nb=32][slot=512] x 16B  (25,165,824 B)
//                     slot = row*4 + p ; row = bl*64+c (bl = bt-2*g2) ; p = d ^ (row&3)
//                     d = n-chunk (8 elems) within the 32-n tile (XOR bank swizzle)
//   kb   @ 25165824 : bf16 B-panels [mt=16][nb=32][slot=768] x 16B  (6,291,456 B)
//                     slot = j*4 + p ; j = k*64+mm ; p = d ^ (j&3)
//   thbf @ 31457280 : bf16 theta^T [o=64][ck=192]                   (24,576 B)
#define APAN_OFF 0
#define KB_OFF   25165824
#define TH_OFF   31457280

// ---------------- prep: convert + transpose + swizzle once ----------------
// Block map: [0,1536) B-panels, [1536,1584) theta, [1584,7728) A-panels.
__global__ __launch_bounds__(256)
void spatio_prep(const float* __restrict__ x, const float* __restrict__ kern,
                 const float* __restrict__ theta,
                 ush* __restrict__ apan, ush* __restrict__ kb, ush* __restrict__ thbf)
{
    const int blk = blockIdx.x;
    const int tid = threadIdx.x;

    if (blk < 1536) {
        // ---- B panels: one 16-B chunk per thread (393,216 chunks) ----
        int ch   = blk * 256 + tid;
        int j    = ch % 192;
        int rest = ch / 192;
        int d    = rest & 3;
        int nb   = (rest >> 2) & 31;
        int mt   = rest >> 7;
        int k    = j >> 6, mm = j & 63;
        int col  = (k << 10) + (mt << 6) + mm;
        u16x8 w;
#pragma unroll
        for (int i = 0; i < 8; ++i) {
            int n = nb * 32 + d * 8 + i;
            w[i] = f2bf(kern[(size_t)n * (NKS * NN) + col]);
        }
        size_t base = ((size_t)(mt * 32 + nb) * 768) + j * 4 + (d ^ (j & 3));
        ((u16x8*)kb)[base] = w;
    } else if (blk < 1584) {
        // ---- theta^T: thbf[o][k*64+c] ----
        int id = (blk - 1536) * 256 + tid;
        if (id < 12288) {
            int row = id >> 6, o = id & 63;   // row = c*3 + k
            int c = row / 3, k = row - 3 * c;
            thbf[o * 192 + k * 64 + c] = f2bf(theta[id]);
        }
    } else {
        // ---- A panels: one 16-B slot per thread (1,572,864 slots) ----
        int id   = (blk - 1584) * 256 + tid;
        int slot = id & 511;
        int g2nb = id >> 9;
        int nb   = g2nb & 31, g2 = g2nb >> 5;
        int row  = slot >> 2, p = slot & 3;
        int d    = p ^ (row & 3);
        int bl   = row >> 6, c = row & 63;
        int bt   = 2 * g2 + bl;
        int b    = bt / NT, t = bt - NT * b;
        const float* src = x + ((size_t)((b * NC + c) * NT + t)) * NN + nb * 32 + d * 8;
        float4 a0 = ((const float4*)src)[0];
        float4 a1 = ((const float4*)src)[1];
        u16x8 w;
        w[0] = f2bf(a0.x); w[1] = f2bf(a0.y); w[2] = f2bf(a0.z); w[3] = f2bf(a0.w);
        w[4] = f2bf(a1.x); w[5] = f2bf(a1.y); w[6] = f2bf(a1.z); w[7] = f2bf(a1.w);
        ((u16x8*)apan)[id] = w;
    }
}

// ---------------- main: 128x192 tile, LDS staging, stash residual, fused stage 2 ----------------
__global__ __launch_bounds__(256, 2)
void spatio_main(const ush* __restrict__ apan, const ush* __restrict__ kb,
                 const ush* __restrict__ thbf, const float* __restrict__ bias,
                 float* __restrict__ out)
{
    // LDS: stage1 As[128][32]@0 (8 KB) + Bs[192][32]@8192 (12 KB)
    //      stage2 xm[64][200]@0 (25.6 KB)  (overlaps As/Bs after stage 1)
    //      stash  stL[128][32]@25600 + stH[128][32]@33792 (16 KB, persists)
    __shared__ __attribute__((aligned(128))) char smem[41984];
    ush (*As)[32]  = (ush (*)[32])smem;
    ush (*Bs)[32]  = (ush (*)[32])(smem + 8192);
    ush (*xm)[200] = (ush (*)[200])smem;
    ush (*stL)[32] = (ush (*)[32])(smem + 25600);
    ush (*stH)[32] = (ush (*)[32])(smem + 33792);

    const int tid  = threadIdx.x;
    const int g2   = blockIdx.x;          // bt-pair 0..95
    const int mt   = blockIdx.y;          // m-tile 0..15
    const int m_base = mt * 64;
    const int lane = tid & 63;
    const int wid  = tid >> 6;            // 0..3
    const int wr   = wid & 1;             // bt half (64 rows)
    const int wn   = wid >> 1;            // col half (96 j)
    const int quad = lane >> 4;
    const int l16  = lane & 15;
    const int pofs = (quad ^ (l16 & 3)) * 8;   // swizzled 16-B chunk (u16 units)

    const char* apan_c = (const char*)apan + ((size_t)g2 << 18);        // g2*32*512*16
    const char* kb_c   = (const char*)kb + ((size_t)mt * 32 * 768 * 16);

    f32x4 acc[4][6];
#pragma unroll
    for (int i = 0; i < 4; ++i)
#pragma unroll
        for (int j = 0; j < 6; ++j) acc[i][j] = (f32x4){0.f, 0.f, 0.f, 0.f};

    // ===== stage 1: xm = x @ K ; 32 iters of K=32 =====
    for (int it = 0; it < 32; ++it) {
        __syncthreads();                   // previous iter's frag reads done
        const char* asrc = apan_c + ((size_t)it << 13);    // it*8192
        const char* bsrc = kb_c + ((size_t)it * 12288);
#pragma unroll
        for (int i = 0; i < 2; ++i)
            cp16(asrc + (i * 256 + tid) * 16, smem + (i * 256 + tid) * 16);
#pragma unroll
        for (int i = 0; i < 3; ++i)
            cp16(bsrc + (i * 256 + tid) * 16, smem + 8192 + (i * 256 + tid) * 16);
        if ((it >> 1) == mt) {
            // stash de-swizzled residual tile (bf16 x rows for this m-tile)
            char* sb = smem + 25600 + (it & 1) * 8192;
#pragma unroll
            for (int i = 0; i < 2; ++i) {
                int m = i * 256 + tid;
                int slot = (m & ~3) + ((m & 3) ^ ((m >> 2) & 3));
                cp16(asrc + slot * 16, sb + m * 16);
            }
        }
        __syncthreads();

        s16x8 af[4], bf[6];
#pragma unroll
        for (int rb = 0; rb < 4; ++rb)
            af[rb] = *(const s16x8*)&As[64 * wr + 16 * rb + l16][pofs];
#pragma unroll
        for (int jb = 0; jb < 6; ++jb)
            bf[jb] = *(const s16x8*)&Bs[96 * wn + 16 * jb + l16][pofs];
#pragma unroll
        for (int rb = 0; rb < 4; ++rb)
#pragma unroll
            for (int jb = 0; jb < 6; ++jb)
                acc[rb][jb] = __builtin_amdgcn_mfma_f32_16x16x32_bf16(af[rb], bf[jb], acc[rb][jb], 0, 0, 0);
    }

    // ===== stage 2: gc = th^T @ xm ; one bt per pass =====
    float bo[4];
#pragma unroll
    for (int r = 0; r < 4; ++r) bo[r] = bias[16 * wid + 4 * quad + r];

    for (int pass = 0; pass < 2; ++pass) {
        __syncthreads();               // stage-1/previous-pass LDS reads done
        if (wr == pass) {
            // write acc -> xm[mm][k*64+c] (B-operand layout)
#pragma unroll
            for (int rb = 0; rb < 4; ++rb)
#pragma unroll
                for (int jb = 0; jb < 6; ++jb) {
                    int J  = 96 * wn + 16 * jb + l16;
                    int kk = J >> 6, mm = J & 63;
                    int ck0 = kk * 64 + 16 * rb + 4 * quad;
                    u16x4 w;
                    w.x = f2bf(acc[rb][jb].x); w.y = f2bf(acc[rb][jb].y);
                    w.z = f2bf(acc[rb][jb].z); w.w = f2bf(acc[rb][jb].w);
                    *(u16x4*)&xm[mm][ck0] = w;
                }
        }
        __syncthreads();

        f32x4 acc2[4];
#pragma unroll
        for (int jb = 0; jb < 4; ++jb) acc2[jb] = (f32x4){0.f, 0.f, 0.f, 0.f};
#pragma unroll
        for (int ks = 0; ks < 6; ++ks) {       // K = 192
            s16x8 a2 = *(const s16x8*)(thbf + (size_t)(16 * wid + l16) * 192 + ks * 32 + quad * 8);
#pragma unroll
            for (int jb = 0; jb < 4; ++jb) {
                s16x8 b2 = *(const s16x8*)&xm[16 * jb + l16][ks * 32 + quad * 8];
                acc2[jb] = __builtin_amdgcn_mfma_f32_16x16x32_bf16(a2, b2, acc2[jb], 0, 0, 0);
            }
        }

        // epilogue: out = relu(gc + bias + x_bf16) ; residual from LDS stash
        const int bt = 2 * g2 + pass;
        const int b2i = bt / NT, t2 = bt - NT * b2i;
#pragma unroll
        for (int jb = 0; jb < 4; ++jb) {
            int mm = 16 * jb + l16;
#pragma unroll
            for (int r = 0; r < 4; ++r) {
                int o = 16 * wid + 4 * quad + r;
                int row = pass * 64 + o;
                ush rv = (jb < 2) ? stL[row][mm] : stH[row][mm - 32];
                size_t idx = (((size_t)(b2i * NC + o) * NT + t2) * NN) + m_base + mm;
                float v = acc2[jb][r] + bo[r] + bf2f(rv);
                out[idx] = fmaxf(v, 0.f);
            }
        }
    }
}

extern "C" void kernel_launch(void* const* d_in, const int* in_sizes, int n_in,
                              void* d_out, int out_size, void* d_ws, size_t ws_size,
                              hipStream_t stream) {
    const float* x     = (const float*)d_in[0];
    const float* kern  = (const float*)d_in[1];
    const float* theta = (const float*)d_in[2];
    const float* bias  = (const float*)d_in[3];
    float* out = (float*)d_out;
    (void)in_sizes; (void)n_in; (void)out_size; (void)ws_size;

    ush* apan = (ush*)((char*)d_ws + APAN_OFF);
    ush* kbp  = (ush*)((char*)d_ws + KB_OFF);
    ush* thbf = (ush*)((char*)d_ws + TH_OFF);

    hipLaunchKernelGGL(spatio_prep, dim3(7728), dim3(256), 0, stream,
                       x, kern, theta, apan, kbp, thbf);
    hipLaunchKernelGGL(spatio_main, dim3(96, 16), dim3(256), 0, stream,
                       apan, kbp, thbf, bias, out);
}

// Round 6
// 186.257 us; speedup vs baseline: 1.5398x; 1.0125x over previous
//
#include <hip/hip_runtime.h>

// SpatioConvLayer: B=16, C_IN=C_OUT=64, T=12, N=1024, KS=3
#define NB   16
#define NC   64
#define NT   12
#define NN   1024
#define NKS  3

typedef float  f32x4  __attribute__((ext_vector_type(4)));
typedef short  s16x8  __attribute__((ext_vector_type(8)));
typedef unsigned short u16x4 __attribute__((ext_vector_type(4)));
typedef unsigned short u16x8 __attribute__((ext_vector_type(8)));
typedef unsigned short ush;

__device__ __forceinline__ ush f2bf(float f) {
    union { float f; unsigned u; } v; v.f = f;
    unsigned r = v.u + 0x7FFFu + ((v.u >> 16) & 1u);   // RNE
    return (ush)(r >> 16);
}
__device__ __forceinline__ float bf2f(ush h) {
    union { unsigned u; float f; } v; v.u = ((unsigned)h) << 16;
    return v.f;
}

// async 16-B global -> LDS (dest must be wave-uniform base + lane*16)
__device__ __forceinline__ void cp16(const void* g, void* l) {
    __builtin_amdgcn_global_load_lds(
        (const __attribute__((address_space(1))) unsigned int*)g,
        (__attribute__((address_space(3))) unsigned int*)l, 16, 0, 0);
}

// Workspace layout:
//   apan @ 0        : bf16 A-panels [g2=96][nb=32][slot=512] x 16B  (25,165,824 B)
//                     slot = row*4 + p ; row = bl*64+c (bl = bt-2*g2) ; p = d ^ (row&3)
//   kb   @ 25165824 : bf16 B-panels [mt=16][nb=32][slot=768] x 16B  (6,291,456 B)
//                     slot = j*4 + p ; j = k*64+mm ; p = d ^ (j&3)
//   thbf @ 31457280 : bf16 theta^T [o=64][ck=192]                   (24,576 B)
#define APAN_OFF 0
#define KB_OFF   25165824
#define TH_OFF   31457280

// ---------------- prep: convert + transpose + swizzle once ----------------
// Block map: [0,1536) B-panels (write-centric), [1536,1584) theta, [1584,7728) A-panels.
__global__ __launch_bounds__(256)
void spatio_prep(const float* __restrict__ x, const float* __restrict__ kern,
                 const float* __restrict__ theta,
                 ush* __restrict__ apan, ush* __restrict__ kb, ush* __restrict__ thbf)
{
    const int blk = blockIdx.x;
    const int tid = threadIdx.x;

    if (blk < 1536) {
        // ---- B panels: thread = output 16-B chunk (writes perfectly linear) ----
        int ch   = blk * 256 + tid;            // 0..393215 == (mt*32+nb)*768 + j*4 + p
        int p    = ch & 3;
        int j    = (ch >> 2) % 192;
        int rest = (ch >> 2) / 192;            // mt*32 + nb
        int nb   = rest & 31, mt = rest >> 5;
        int d    = p ^ (j & 3);
        int k    = j >> 6, mm = j & 63;
        int col  = (k << 10) + (mt << 6) + mm;
        u16x8 w;
#pragma unroll
        for (int i = 0; i < 8; ++i) {
            int n = nb * 32 + d * 8 + i;
            w[i] = f2bf(kern[(size_t)n * (NKS * NN) + col]);
        }
        ((u16x8*)kb)[ch] = w;
    } else if (blk < 1584) {
        // ---- theta^T: thbf[o][k*64+c] ----
        int id = (blk - 1536) * 256 + tid;
        if (id < 12288) {
            int row = id >> 6, o = id & 63;   // row = c*3 + k
            int c = row / 3, k = row - 3 * c;
            thbf[o * 192 + k * 64 + c] = f2bf(theta[id]);
        }
    } else {
        // ---- A panels: one 16-B slot per thread (linear writes, coalesced reads) ----
        int id   = (blk - 1584) * 256 + tid;
        int slot = id & 511;
        int g2nb = id >> 9;
        int nb   = g2nb & 31, g2 = g2nb >> 5;
        int row  = slot >> 2, p = slot & 3;
        int d    = p ^ (row & 3);
        int bl   = row >> 6, c = row & 63;
        int bt   = 2 * g2 + bl;
        int b    = bt / NT, t = bt - NT * b;
        const float* src = x + ((size_t)((b * NC + c) * NT + t)) * NN + nb * 32 + d * 8;
        float4 a0 = ((const float4*)src)[0];
        float4 a1 = ((const float4*)src)[1];
        u16x8 w;
        w[0] = f2bf(a0.x); w[1] = f2bf(a0.y); w[2] = f2bf(a0.z); w[3] = f2bf(a0.w);
        w[4] = f2bf(a1.x); w[5] = f2bf(a1.y); w[6] = f2bf(a1.z); w[7] = f2bf(a1.w);
        ((u16x8*)apan)[id] = w;
    }
}

// ---------------- main: 128x192 tile, double-buffered 1-barrier K-loop ----------------
__global__ __launch_bounds__(256, 2)
void spatio_main(const ush* __restrict__ apan, const ush* __restrict__ kb,
                 const ush* __restrict__ thbf, const float* __restrict__ bias,
                 float* __restrict__ out)
{
    // LDS: buf[p] @ p*20480 : As[128][32] (8 KB) + Bs[192][32] (12 KB)
    //      stash @40960: stL[128][32] + stH[128][32] (16 KB, persists)
    //      stage2 xm[64][200] overlays @0 (25.6 KB) after stage 1
    __shared__ __attribute__((aligned(128))) char smem[57344];
    ush (*xm)[200] = (ush (*)[200])smem;
    ush (*stL)[32] = (ush (*)[32])(smem + 40960);
    ush (*stH)[32] = (ush (*)[32])(smem + 49152);

    const int tid  = threadIdx.x;
    const int g2   = blockIdx.x;          // bt-pair 0..95
    const int mt   = blockIdx.y;          // m-tile 0..15
    const int m_base = mt * 64;
    const int lane = tid & 63;
    const int wid  = tid >> 6;            // 0..3
    const int wr   = wid & 1;             // bt half (64 rows)
    const int wn   = wid >> 1;            // col half (96 j)
    const int quad = lane >> 4;
    const int l16  = lane & 15;
    const int pofs = (quad ^ (l16 & 3)) * 8;   // swizzled 16-B chunk (u16 units)

    const char* apan_c = (const char*)apan + ((size_t)g2 << 18);        // g2*32*512*16
    const char* kb_c   = (const char*)kb + ((size_t)mt * 32 * 768 * 16);

    f32x4 acc[4][6];
#pragma unroll
    for (int i = 0; i < 4; ++i)
#pragma unroll
        for (int j = 0; j < 6; ++j) acc[i][j] = (f32x4){0.f, 0.f, 0.f, 0.f};

    // prologue: preload iter 0 into buf0
#pragma unroll
    for (int i = 0; i < 2; ++i)
        cp16(apan_c + (i * 256 + tid) * 16, smem + (i * 256 + tid) * 16);
#pragma unroll
    for (int i = 0; i < 3; ++i)
        cp16(kb_c + (i * 256 + tid) * 16, smem + 8192 + (i * 256 + tid) * 16);

    // ===== stage 1: xm = x @ K ; 32 iters, 1 barrier/iter, dbuf =====
    for (int it = 0; it < 32; ++it) {
        const int p = it & 1;
        char* buf = smem + p * 20480;
        __syncthreads();                   // buf[p] loads complete; buf[p^1] readers (it-1) done
        if (it < 31) {                     // prefetch it+1 into buf[p^1]
            const char* asrc = apan_c + ((size_t)(it + 1) << 13);
            const char* bsrc = kb_c + (size_t)(it + 1) * 12288;
            char* nbuf = smem + (p ^ 1) * 20480;
#pragma unroll
            for (int i = 0; i < 2; ++i)
                cp16(asrc + (i * 256 + tid) * 16, nbuf + (i * 256 + tid) * 16);
#pragma unroll
            for (int i = 0; i < 3; ++i)
                cp16(bsrc + (i * 256 + tid) * 16, nbuf + 8192 + (i * 256 + tid) * 16);
        }
        if ((it >> 1) == mt) {
            // stash de-swizzled residual tile (bf16 x rows for this m-tile)
            const char* asrc = apan_c + ((size_t)it << 13);
            char* sb = smem + 40960 + (it & 1) * 8192;
#pragma unroll
            for (int i = 0; i < 2; ++i) {
                int m = i * 256 + tid;
                int slot = (m & ~3) + ((m & 3) ^ ((m >> 2) & 3));
                cp16(asrc + slot * 16, sb + m * 16);
            }
        }

        ush (*As)[32] = (ush (*)[32])buf;
        ush (*Bs)[32] = (ush (*)[32])(buf + 8192);
        s16x8 af[4], bf[6];
#pragma unroll
        for (int rb = 0; rb < 4; ++rb)
            af[rb] = *(const s16x8*)&As[64 * wr + 16 * rb + l16][pofs];
#pragma unroll
        for (int jb = 0; jb < 6; ++jb)
            bf[jb] = *(const s16x8*)&Bs[96 * wn + 16 * jb + l16][pofs];
#pragma unroll
        for (int rb = 0; rb < 4; ++rb)
#pragma unroll
            for (int jb = 0; jb < 6; ++jb)
                acc[rb][jb] = __builtin_amdgcn_mfma_f32_16x16x32_bf16(af[rb], bf[jb], acc[rb][jb], 0, 0, 0);
    }

    // ===== stage 2: gc = th^T @ xm ; one bt per pass =====
    float bo[4];
#pragma unroll
    for (int r = 0; r < 4; ++r) bo[r] = bias[16 * wid + 4 * quad + r];

    for (int pass = 0; pass < 2; ++pass) {
        __syncthreads();               // stage-1/previous-pass LDS reads done
        if (wr == pass) {
            // write acc -> xm[mm][k*64+c] (B-operand layout)
#pragma unroll
            for (int rb = 0; rb < 4; ++rb)
#pragma unroll
                for (int jb = 0; jb < 6; ++jb) {
                    int J  = 96 * wn + 16 * jb + l16;
                    int kk = J >> 6, mm = J & 63;
                    int ck0 = kk * 64 + 16 * rb + 4 * quad;
                    u16x4 w;
                    w.x = f2bf(acc[rb][jb].x); w.y = f2bf(acc[rb][jb].y);
                    w.z = f2bf(acc[rb][jb].z); w.w = f2bf(acc[rb][jb].w);
                    *(u16x4*)&xm[mm][ck0] = w;
                }
        }
        __syncthreads();

        f32x4 acc2[4];
#pragma unroll
        for (int jb = 0; jb < 4; ++jb) acc2[jb] = (f32x4){0.f, 0.f, 0.f, 0.f};
#pragma unroll
        for (int ks = 0; ks < 6; ++ks) {       // K = 192
            s16x8 a2 = *(const s16x8*)(thbf + (size_t)(16 * wid + l16) * 192 + ks * 32 + quad * 8);
#pragma unroll
            for (int jb = 0; jb < 4; ++jb) {
                s16x8 b2 = *(const s16x8*)&xm[16 * jb + l16][ks * 32 + quad * 8];
                acc2[jb] = __builtin_amdgcn_mfma_f32_16x16x32_bf16(a2, b2, acc2[jb], 0, 0, 0);
            }
        }

        // epilogue: out = relu(gc + bias + x_bf16) ; residual from LDS stash
        const int bt = 2 * g2 + pass;
        const int b2i = bt / NT, t2 = bt - NT * b2i;
#pragma unroll
        for (int jb = 0; jb < 4; ++jb) {
            int mm = 16 * jb + l16;
#pragma unroll
            for (int r = 0; r < 4; ++r) {
                int o = 16 * wid + 4 * quad + r;
                int row = pass * 64 + o;
                ush rv = (jb < 2) ? stL[row][mm] : stH[row][mm - 32];
                size_t idx = (((size_t)(b2i * NC + o) * NT + t2) * NN) + m_base + mm;
                float v = acc2[jb][r] + bo[r] + bf2f(rv);
                out[idx] = fmaxf(v, 0.f);
            }
        }
    }
}

extern "C" void kernel_launch(void* const* d_in, const int* in_sizes, int n_in,
                              void* d_out, int out_size, void* d_ws, size_t ws_size,
                              hipStream_t stream) {
    const float* x     = (const float*)d_in[0];
    const float* kern  = (const float*)d_in[1];
    const float* theta = (const float*)d_in[2];
    const float* bias  = (const float*)d_in[3];
    float* out = (float*)d_out;
    (void)in_sizes; (void)n_in; (void)out_size; (void)ws_size;

    ush* apan = (ush*)((char*)d_ws + APAN_OFF);
    ush* kbp  = (ush*)((char*)d_ws + KB_OFF);
    ush* thbf = (ush*)((char*)d_ws + TH_OFF);

    hipLaunchKernelGGL(spatio_prep, dim3(7728), dim3(256), 0, stream,
                       x, kern, theta, apan, kbp, thbf);
    hipLaunchKernelGGL(spatio_main, dim3(96, 16), dim3(256), 0, stream,
                       apan, kbp, thbf, bias, out);
}